// Round 1
// baseline (283.112 us; speedup 1.0000x reference)
//
#include <hip/hip_runtime.h>
#include <math.h>

typedef _Float16 half8  __attribute__((ext_vector_type(8)));
typedef float    float4v __attribute__((ext_vector_type(4)));

constexpr int T_ = 1 << 18;            // hash table size per level
constexpr unsigned TMASK = T_ - 1;
constexpr unsigned PRIME = 2654435761u;
constexpr int HP = 72;                 // H row pitch in f16 (64 + 8 pad: bank-spread)

// ws layout:
//   [0, 22528)      : 22 W-fragments (f16), frag f: 64 lanes x 8 halfs
//                     frag order: L1 t=0..3 | L2 s0 t0..3, s1 t0..3 | L3 ditto | L4 s0,s1
//   [22528, 23360)  : biases fp32: b1[64] b2[64] b3[64] b4[16] (b4 padded w/ zeros)
//   [23360, 23424)  : N_values fp32 [16]
constexpr int WFRAG_HALFS = 22 * 64 * 8;   // 11264 halfs = 22528 B
constexpr int BIAS_FLOATS = 208;           // 3*64 + 16
constexpr int WS_UINT4    = 23424 / 16;    // 1464

struct NVals { float n[16]; };

// ---------------- prep: swizzle weights into MFMA fragment order ----------------
__global__ void prep_weights(const float* __restrict__ W1, const float* __restrict__ b1,
                             const float* __restrict__ W2, const float* __restrict__ b2,
                             const float* __restrict__ W3, const float* __restrict__ b3,
                             const float* __restrict__ W4, const float* __restrict__ b4,
                             _Float16* __restrict__ wsW, float* __restrict__ wsB, NVals nv)
{
    const int tid = threadIdx.x;
    // A'-fragment (weights-as-A, transposed formulation): lane l holds
    // W[k = 32s + 8*(l>>4) + j][n = 16t + (l&15)], j=0..7 contiguous.
    for (int e = tid; e < WFRAG_HALFS; e += 256) {
        const int frag = e >> 9;         // /512
        const int l    = (e >> 3) & 63;
        const int j    = e & 7;
        const int g = l >> 4, m = l & 15;
        float v;
        if (frag < 4) {                       // L1: W1 (32x64), s=0, t=frag
            v = W1[(8*g + j) * 64 + 16*frag + m];
        } else if (frag < 12) {               // L2: W2 (64x64)
            const int s = (frag - 4) >> 2, t = (frag - 4) & 3;
            v = W2[(32*s + 8*g + j) * 64 + 16*t + m];
        } else if (frag < 20) {               // L3: W3 (64x64)
            const int s = (frag - 12) >> 2, t = (frag - 12) & 3;
            v = W3[(32*s + 8*g + j) * 64 + 16*t + m];
        } else {                              // L4: W4 (64x3), t=0, pad n>=3 with 0
            const int s = frag - 20;
            v = (m < 3) ? W4[(32*s + 8*g + j) * 3 + m] : 0.f;
        }
        wsW[e] = (_Float16)v;
    }
    if (tid < 64) { wsB[tid] = b1[tid]; wsB[64 + tid] = b2[tid]; wsB[128 + tid] = b3[tid]; }
    if (tid >= 64 && tid < 80) { const int r = tid - 64; wsB[192 + r] = (r < 3) ? b4[r] : 0.f; }
    if (tid >= 80 && tid < 96) wsB[BIAS_FLOATS + (tid - 80)] = nv.n[tid - 80];
}

// ---------------- main fused kernel ----------------
// Block = 256 thr = 4 waves. Each wave: 4 tiles of 16 points (64 pts), block = 256 pts.
// Transposed MFMA form: D[n_out][pt] = W^T x H^T ; activations are B-operand
// (B[n=lane&15=point][k=(lane>>4)*8+j]), so the encoder writes fragments directly
// and all H relayout is b64-write / b128-read. Per-wave H buffer -> no __syncthreads
// in the loop (in-order DS pipe + lgkmcnt fences give wave-local RAW ordering).
//
// R1 changes vs baseline (theory: latency-bound on scattered table gathers):
//   (a) corner (0,0) hashes to index 0 for every point -> v0 = table[lv*T] is a
//       per-level CONSTANT; hoisted to registers (removes 25% of all gathers).
//   (b) software pipeline: tile it+1's 12 scattered gathers are ISSUED before
//       tile it's MLP and consumed next iteration -> gather latency hides under
//       MFMA + LDS round-trips. lgkmcnt-only fences leave vmcnt in flight;
//       sched_barrier(0) pins the issue point before the MLP.
#define DS_FENCE() __asm__ volatile("s_waitcnt lgkmcnt(0)" ::: "memory")

struct Gather {                // pipeline state: 32 VGPRs
    float  fx[4], fy[4];
    float2 v1[4], v2[4], v3[4];
};

__device__ __forceinline__ void issue_gather(Gather& G, const float2 xy,
                                             const float2* __restrict__ table,
                                             const float (&nvq)[4], const int g)
{
    #pragma unroll
    for (int q = 0; q < 4; ++q) {
        const int lv = 4*g + q;
        const float n = nvq[q];
        const float xs = xy.x * n, ys = xy.y * n;
        const float xf = floorf(xs), yf = floorf(ys);
        G.fx[q] = xs - xf; G.fy[q] = ys - yf;
        const unsigned xi = (unsigned)(int)xf, yi = (unsigned)(int)yf;
        const unsigned yp = yi * PRIME;
        const float2* tl = table + (size_t)lv * T_;
        G.v1[q] = tl[yp & TMASK];          // corner (0, y)
        G.v2[q] = tl[xi & TMASK];          // corner (x, 0)
        G.v3[q] = tl[(xi ^ yp) & TMASK];   // corner (x, y)
    }
}

__device__ __forceinline__ half8 combine_feat(const Gather& G, const float2 (&v0c)[4])
{
    half8 feat;
    #pragma unroll
    for (int q = 0; q < 4; ++q) {
        const float fx = G.fx[q], fy = G.fy[q];
        const float cx = 1.f - fx, cy = 1.f - fy;
        const float w0 = cx*cy, w1 = cx*fy, w2 = fx*cy, w3 = fx*fy;
        feat[2*q+0] = (_Float16)(w0*v0c[q].x + w1*G.v1[q].x + w2*G.v2[q].x + w3*G.v3[q].x);
        feat[2*q+1] = (_Float16)(w0*v0c[q].y + w1*G.v1[q].y + w2*G.v2[q].y + w3*G.v3[q].y);
    }
    return feat;
}

__global__ __launch_bounds__(256, 2)
void fused_hashnerf_mfma(const float2* __restrict__ X,
                         const float2* __restrict__ table,
                         const uint4* __restrict__ ws,
                         float* __restrict__ out)
{
    __shared__ uint4    sRaw[WS_UINT4];        // W frags (f16) + biases + N_values
    __shared__ _Float16 sH[4][16 * HP];        // per-wave activation buffer

    const int tid = threadIdx.x;
    for (int i = tid; i < WS_UINT4; i += 256) sRaw[i] = ws[i];
    __syncthreads();

    const _Float16* Wl = (const _Float16*)sRaw;
    const float*    Bl = (const float*)(sRaw + (22528 / 16));

    const int wave = tid >> 6, lane = tid & 63;
    const int g = lane >> 4, c = lane & 15;
    _Float16* H = &sH[wave][0];

    // loop-invariant bias fragments: C'[n_out = 16t + 4g + r][pt], init = b[n_out]
    float4v b1f[4], b2f[4], b3f[4], b4f;
    #pragma unroll
    for (int t = 0; t < 4; ++t) {
        b1f[t] = *(const float4v*)(Bl +       16*t + 4*g);
        b2f[t] = *(const float4v*)(Bl +  64 + 16*t + 4*g);
        b3f[t] = *(const float4v*)(Bl + 128 + 16*t + 4*g);
    }
    b4f = *(const float4v*)(Bl + 192 + 4*g);   // zeros for g>0 / n_out>=3
    float nvq[4];
    #pragma unroll
    for (int q = 0; q < 4; ++q) nvq[q] = Bl[BIAS_FLOATS + 4*g + q];

    const int base_pt = blockIdx.x * 256 + wave * 64;

    // X for all 4 tiles (coalesced, issued up front)
    float2 xy[4];
    #pragma unroll
    for (int it = 0; it < 4; ++it) xy[it] = X[base_pt + it*16 + c];

    // per-level constant corner (0,0): v0 = table[lv*T + 0]
    float2 v0c[4];
    #pragma unroll
    for (int q = 0; q < 4; ++q) v0c[q] = table[(size_t)(4*g + q) * T_];

    Gather GA, GB;
    issue_gather(GA, xy[0], table, nvq, g);    // prologue: tile 0 in flight

    #pragma unroll
    for (int it = 0; it < 4; ++it) {
        Gather& Gc = (it & 1) ? GB : GA;       // static after unroll
        Gather& Gn = (it & 1) ? GA : GB;

        // ---- consume tile it's gathers (vmcnt wait lands here) ----
        const half8 feat = combine_feat(Gc, v0c);

        // ---- issue tile it+1's gathers; they fly during the MLP below ----
        if (it < 3) issue_gather(Gn, xy[it+1], table, nvq, g);
        __builtin_amdgcn_sched_barrier(0);     // pin loads before the MLP

        // ---- L1: acc[t] = W1^T(tile t) x feat + b1 ----
        float4v acc[4];
        #pragma unroll
        for (int t = 0; t < 4; ++t) {
            const half8 wf = *(const half8*)(Wl + (t*64 + lane)*8);
            acc[t] = __builtin_amdgcn_mfma_f32_16x16x32_f16(wf, feat, b1f[t], 0, 0, 0);
        }
        // leaky + f16 + write H[pt c][16t+4g .. +3]  (b64)
        #pragma unroll
        for (int t = 0; t < 4; ++t) {
            union { _Float16 h[4]; float2 f2; } u;
            #pragma unroll
            for (int r = 0; r < 4; ++r) {
                const float v = acc[t][r];
                u.h[r] = (_Float16)(v > 0.f ? v : 0.01f * v);
            }
            *(float2*)(H + c*HP + 16*t + 4*g) = u.f2;
        }
        DS_FENCE();

        // ---- L2 ----
        half8 a0 = *(const half8*)(H + c*HP +      8*g);
        half8 a1 = *(const half8*)(H + c*HP + 32 + 8*g);
        float4v acc2[4];
        #pragma unroll
        for (int t = 0; t < 4; ++t) {
            const half8 w0f = *(const half8*)(Wl + ((4 + t)*64 + lane)*8);
            const half8 w1f = *(const half8*)(Wl + ((8 + t)*64 + lane)*8);
            float4v a = __builtin_amdgcn_mfma_f32_16x16x32_f16(w0f, a0, b2f[t], 0, 0, 0);
            acc2[t]   = __builtin_amdgcn_mfma_f32_16x16x32_f16(w1f, a1, a,      0, 0, 0);
        }
        #pragma unroll
        for (int t = 0; t < 4; ++t) {
            union { _Float16 h[4]; float2 f2; } u;
            #pragma unroll
            for (int r = 0; r < 4; ++r) {
                const float v = acc2[t][r];
                u.h[r] = (_Float16)(v > 0.f ? v : 0.01f * v);
            }
            *(float2*)(H + c*HP + 16*t + 4*g) = u.f2;
        }
        DS_FENCE();

        // ---- L3 ----
        a0 = *(const half8*)(H + c*HP +      8*g);
        a1 = *(const half8*)(H + c*HP + 32 + 8*g);
        float4v acc3[4];
        #pragma unroll
        for (int t = 0; t < 4; ++t) {
            const half8 w0f = *(const half8*)(Wl + ((12 + t)*64 + lane)*8);
            const half8 w1f = *(const half8*)(Wl + ((16 + t)*64 + lane)*8);
            float4v a = __builtin_amdgcn_mfma_f32_16x16x32_f16(w0f, a0, b3f[t], 0, 0, 0);
            acc3[t]   = __builtin_amdgcn_mfma_f32_16x16x32_f16(w1f, a1, a,      0, 0, 0);
        }
        #pragma unroll
        for (int t = 0; t < 4; ++t) {
            union { _Float16 h[4]; float2 f2; } u;
            #pragma unroll
            for (int r = 0; r < 4; ++r) {
                const float v = acc3[t][r];
                u.h[r] = (_Float16)(v > 0.f ? v : 0.01f * v);
            }
            *(float2*)(H + c*HP + 16*t + 4*g) = u.f2;
        }
        DS_FENCE();

        // ---- L4: n_out = 0..2 live in lanes g==0 ----
        a0 = *(const half8*)(H + c*HP +      8*g);
        a1 = *(const half8*)(H + c*HP + 32 + 8*g);
        const half8 w40 = *(const half8*)(Wl + (20*64 + lane)*8);
        const half8 w41 = *(const half8*)(Wl + (21*64 + lane)*8);
        float4v o = __builtin_amdgcn_mfma_f32_16x16x32_f16(w40, a0, b4f, 0, 0, 0);
        o         = __builtin_amdgcn_mfma_f32_16x16x32_f16(w41, a1, o,   0, 0, 0);
        if (g == 0) {
            const int p = base_pt + it * 16 + c;
            float* op = out + (size_t)3 * p;
            op[0] = fmaxf(o[0], 0.f);
            op[1] = fmaxf(o[1], 0.f);
            op[2] = fmaxf(o[2], 0.f);
        }
    }
}

extern "C" void kernel_launch(void* const* d_in, const int* in_sizes, int n_in,
                              void* d_out, int out_size, void* d_ws, size_t ws_size,
                              hipStream_t stream) {
    const float2* X     = (const float2*)d_in[0];
    const float2* table = (const float2*)d_in[1];
    const float*  W1    = (const float*)d_in[2];
    const float*  b1    = (const float*)d_in[3];
    const float*  W2    = (const float*)d_in[4];
    const float*  b2    = (const float*)d_in[5];
    const float*  W3    = (const float*)d_in[6];
    const float*  b3    = (const float*)d_in[7];
    const float*  W4    = (const float*)d_in[8];
    const float*  b4    = (const float*)d_in[9];
    float* out          = (float*)d_out;

    const int npts = in_sizes[0] / 2;

    // N_l = floor(float32(16 * b^l)), b computed in double (matches numpy)
    NVals nv;
    const double bg = exp((log(1024.0) - log(16.0)) / 15.0);
    for (int l = 0; l < 16; ++l)
        nv.n[l] = floorf((float)(16.0 * pow(bg, (double)l)));

    _Float16* wsW = (_Float16*)d_ws;
    float*    wsB = (float*)((char*)d_ws + 22528);

    prep_weights<<<1, 256, 0, stream>>>(W1, b1, W2, b2, W3, b3, W4, b4, wsW, wsB, nv);
    fused_hashnerf_mfma<<<npts / 256, 256, 0, stream>>>(X, table, (const uint4*)d_ws, out);
}

// Round 3
// 220.147 us; speedup vs baseline: 1.2860x; 1.2860x over previous
//
#include <hip/hip_runtime.h>
#include <math.h>

typedef _Float16 half8  __attribute__((ext_vector_type(8)));
typedef float    float4v __attribute__((ext_vector_type(4)));

constexpr int T_ = 1 << 18;            // hash table size per level
constexpr unsigned TMASK = T_ - 1;
constexpr unsigned PRIME = 2654435761u;
constexpr int HP = 72;                 // H row pitch in f16 (64 + 8 pad: bank-spread)

// ws layout:
//   [0, 22528)      : 22 W-fragments (f16), frag f: 64 lanes x 8 halfs
//   [22528, 23360)  : biases fp32: b1[64] b2[64] b3[64] b4[16]
//   [23360, 23424)  : N_values fp32 [16]
//   [23424, 23488)  : level offsets fp32 [16] (prefix sum of N_l+1)
constexpr int WFRAG_HALFS = 22 * 64 * 8;   // 11264 halfs = 22528 B
constexpr int BIAS_FLOATS = 208;           // 3*64 + 16
constexpr int WS_BYTES    = 22528 + 240 * 4;   // 23488
constexpr int WS_UINT4    = WS_BYTES / 16;     // 1468
constexpr int MAX_STAGE   = 4224;          // >= sum(N_l+1) = 4179

constexpr int BLK   = 512;                 // threads / block (8 waves)
constexpr int WAVES = 8;
constexpr int PTS_PER_BLOCK = 1024;        // 8 waves x 8 tiles x 16 pts

struct Meta { float n[16]; float off[16]; };

// ---------------- prep: swizzle weights into MFMA fragment order ----------------
// Parallelized over 45 blocks (was 1 block = tens of us of serial time).
__global__ void prep_weights(const float* __restrict__ W1, const float* __restrict__ b1,
                             const float* __restrict__ W2, const float* __restrict__ b2,
                             const float* __restrict__ W3, const float* __restrict__ b3,
                             const float* __restrict__ W4, const float* __restrict__ b4,
                             _Float16* __restrict__ wsW, float* __restrict__ wsB, Meta mv)
{
    const int tid = threadIdx.x;
    if (blockIdx.x < 44) {
        // A'-fragment: lane l holds W[k = 32s + 8*(l>>4) + j][n = 16t + (l&15)]
        const int e = blockIdx.x * 256 + tid;       // 44*256 == WFRAG_HALFS exactly
        const int frag = e >> 9;
        const int l    = (e >> 3) & 63;
        const int j    = e & 7;
        const int g = l >> 4, m = l & 15;
        float v;
        if (frag < 4) {                       // L1: W1 (32x64), s=0, t=frag
            v = W1[(8*g + j) * 64 + 16*frag + m];
        } else if (frag < 12) {               // L2: W2 (64x64)
            const int s = (frag - 4) >> 2, t = (frag - 4) & 3;
            v = W2[(32*s + 8*g + j) * 64 + 16*t + m];
        } else if (frag < 20) {               // L3: W3 (64x64)
            const int s = (frag - 12) >> 2, t = (frag - 12) & 3;
            v = W3[(32*s + 8*g + j) * 64 + 16*t + m];
        } else {                              // L4: W4 (64x3), pad n>=3 with 0
            const int s = frag - 20;
            v = (m < 3) ? W4[(32*s + 8*g + j) * 3 + m] : 0.f;
        }
        wsW[e] = (_Float16)v;
    } else {
        if (tid < 64) { wsB[tid] = b1[tid]; wsB[64 + tid] = b2[tid]; wsB[128 + tid] = b3[tid]; }
        else if (tid < 80)  { const int r = tid - 64; wsB[192 + r] = (r < 3) ? b4[r] : 0.f; }
        else if (tid < 96)  wsB[BIAS_FLOATS + (tid - 80)] = mv.n[tid - 80];
        else if (tid < 112) wsB[BIAS_FLOATS + 16 + (tid - 96)] = mv.off[tid - 96];
    }
}

// ---------------- main fused kernel ----------------
// Theory: bottleneck = scattered VMEM transaction throughput (TA/L2/L3 path),
// NOT latency (R1 pipeline was null) and NOT occupancy (39->30% was null).
// Eliminate 2 of the 3 scattered gathers per (point, level):
//   v2 = tl[xi]            : xi <= N_l -> first N_l+1 entries of each level.
//                            Staged into LDS with COALESCED loads (~33 KB).
//   v1 = tl[(yi*P)&MASK]   : only N_l+1 distinct targets (yi <= N_l).
//                            Staged into a yi-indexed LDS array; the ~4.2K
//                            scattered staging loads amortize over 1024 pts/block.
//   v3 = tl[(xi^yp)&MASK]  : genuinely 2D-random -> stays a pipelined gather.
// Scattered requests/pt: 48 -> ~20. Staged values are identical f32 bits -> exact.
#define DS_FENCE() __asm__ volatile("s_waitcnt lgkmcnt(0)" ::: "memory")

struct Gather {                // pipeline state
    float  fx[4], fy[4];
    float2 v1[4], v2[4], v3[4];
};

__device__ __forceinline__ void issue_gather(Gather& G, const float2 xy,
                                             const float2* __restrict__ table,
                                             const float (&nvq)[4], const int (&offq)[4],
                                             const float2* __restrict__ sV1,
                                             const float2* __restrict__ sV2, const int g)
{
    #pragma unroll
    for (int q = 0; q < 4; ++q) {
        const int lv = 4*g + q;
        const float n = nvq[q];
        const float xs = xy.x * n, ys = xy.y * n;
        const float xf = floorf(xs), yf = floorf(ys);
        G.fx[q] = xs - xf; G.fy[q] = ys - yf;
        const unsigned xi = (unsigned)(int)xf, yi = (unsigned)(int)yf;
        const unsigned yp = yi * PRIME;
        G.v3[q] = table[(size_t)lv * T_ + ((xi ^ yp) & TMASK)];  // VMEM gather (in flight)
        G.v1[q] = sV1[offq[q] + (int)yi];                        // LDS
        G.v2[q] = sV2[offq[q] + (int)xi];                        // LDS
    }
}

__device__ __forceinline__ half8 combine_feat(const Gather& G, const float2 (&v0c)[4])
{
    half8 feat;
    #pragma unroll
    for (int q = 0; q < 4; ++q) {
        const float fx = G.fx[q], fy = G.fy[q];
        const float cx = 1.f - fx, cy = 1.f - fy;
        const float w0 = cx*cy, w1 = cx*fy, w2 = fx*cy, w3 = fx*fy;
        feat[2*q+0] = (_Float16)(w0*v0c[q].x + w1*G.v1[q].x + w2*G.v2[q].x + w3*G.v3[q].x);
        feat[2*q+1] = (_Float16)(w0*v0c[q].y + w1*G.v1[q].y + w2*G.v2[q].y + w3*G.v3[q].y);
    }
    return feat;
}

__global__ __launch_bounds__(BLK)
void fused_hashnerf_mfma(const float2* __restrict__ X,
                         const float2* __restrict__ table,
                         const uint4* __restrict__ ws,
                         float* __restrict__ out)
{
    __shared__ uint4    sRaw[WS_UINT4];        // W frags (f16) + biases + meta
    __shared__ _Float16 sH[WAVES][16 * HP];    // per-wave activation buffer
    __shared__ float2   sV1[MAX_STAGE];        // tl[(i*PRIME)&TMASK], yi-indexed
    __shared__ float2   sV2[MAX_STAGE];        // tl[i], xi-indexed

    const int tid = threadIdx.x;
    for (int i = tid; i < WS_UINT4; i += BLK) sRaw[i] = ws[i];
    __syncthreads();

    const _Float16* Wl = (const _Float16*)sRaw;
    const float*    Bl = (const float*)(sRaw + (22528 / 16));

    // ---- stage per-level v1/v2 tables into LDS ----
    {
        const float* NVp = Bl + BIAS_FLOATS;
        const float* OFp = Bl + BIAS_FLOATS + 16;
        for (int l = 0; l < 16; ++l) {
            const int nl  = (int)NVp[l];
            const int off = (int)OFp[l];
            const float2* tl = table + (size_t)l * T_;
            for (int i = tid; i <= nl; i += BLK) {
                sV2[off + i] = tl[i];                              // coalesced
                sV1[off + i] = tl[((unsigned)i * PRIME) & TMASK];  // scattered, amortized
            }
        }
    }
    __syncthreads();

    const int wave = tid >> 6, lane = tid & 63;
    const int g = lane >> 4, c = lane & 15;
    _Float16* H = &sH[wave][0];

    // loop-invariant bias fragments: C'[n_out = 16t + 4g + r][pt]
    float4v b1f[4], b2f[4], b3f[4], b4f;
    #pragma unroll
    for (int t = 0; t < 4; ++t) {
        b1f[t] = *(const float4v*)(Bl +       16*t + 4*g);
        b2f[t] = *(const float4v*)(Bl +  64 + 16*t + 4*g);
        b3f[t] = *(const float4v*)(Bl + 128 + 16*t + 4*g);
    }
    b4f = *(const float4v*)(Bl + 192 + 4*g);
    float nvq[4];
    int   offq[4];
    #pragma unroll
    for (int q = 0; q < 4; ++q) {
        nvq[q]  = Bl[BIAS_FLOATS + 4*g + q];
        offq[q] = (int)Bl[BIAS_FLOATS + 16 + 4*g + q];
    }

    const int base_pt = blockIdx.x * PTS_PER_BLOCK + wave * 128;

    // X for all 8 tiles (coalesced, static indices after unroll)
    float2 xy[8];
    #pragma unroll
    for (int it = 0; it < 8; ++it) xy[it] = X[base_pt + it*16 + c];

    // per-level constant corner (0,0): v0 = table[lv*T + 0]
    float2 v0c[4];
    #pragma unroll
    for (int q = 0; q < 4; ++q) v0c[q] = table[(size_t)(4*g + q) * T_];

    Gather GA, GB;
    issue_gather(GA, xy[0], table, nvq, offq, sV1, sV2, g);

    #pragma unroll
    for (int it = 0; it < 8; ++it) {
        Gather& Gc = (it & 1) ? GB : GA;       // static after unroll
        Gather& Gn = (it & 1) ? GA : GB;

        // ---- consume tile it (vmcnt wait for v3 lands here) ----
        const half8 feat = combine_feat(Gc, v0c);

        // ---- issue tile it+1's v3 gathers; they fly during the MLP below ----
        if (it < 7) issue_gather(Gn, xy[it+1], table, nvq, offq, sV1, sV2, g);
        __builtin_amdgcn_sched_barrier(0);

        // ---- L1 ----
        float4v acc[4];
        #pragma unroll
        for (int t = 0; t < 4; ++t) {
            const half8 wf = *(const half8*)(Wl + (t*64 + lane)*8);
            acc[t] = __builtin_amdgcn_mfma_f32_16x16x32_f16(wf, feat, b1f[t], 0, 0, 0);
        }
        #pragma unroll
        for (int t = 0; t < 4; ++t) {
            union { _Float16 h[4]; float2 f2; } u;
            #pragma unroll
            for (int r = 0; r < 4; ++r) {
                const float v = acc[t][r];
                u.h[r] = (_Float16)(v > 0.f ? v : 0.01f * v);
            }
            *(float2*)(H + c*HP + 16*t + 4*g) = u.f2;
        }
        DS_FENCE();

        // ---- L2 ----
        half8 a0 = *(const half8*)(H + c*HP +      8*g);
        half8 a1 = *(const half8*)(H + c*HP + 32 + 8*g);
        float4v acc2[4];
        #pragma unroll
        for (int t = 0; t < 4; ++t) {
            const half8 w0f = *(const half8*)(Wl + ((4 + t)*64 + lane)*8);
            const half8 w1f = *(const half8*)(Wl + ((8 + t)*64 + lane)*8);
            float4v a = __builtin_amdgcn_mfma_f32_16x16x32_f16(w0f, a0, b2f[t], 0, 0, 0);
            acc2[t]   = __builtin_amdgcn_mfma_f32_16x16x32_f16(w1f, a1, a,      0, 0, 0);
        }
        #pragma unroll
        for (int t = 0; t < 4; ++t) {
            union { _Float16 h[4]; float2 f2; } u;
            #pragma unroll
            for (int r = 0; r < 4; ++r) {
                const float v = acc2[t][r];
                u.h[r] = (_Float16)(v > 0.f ? v : 0.01f * v);
            }
            *(float2*)(H + c*HP + 16*t + 4*g) = u.f2;
        }
        DS_FENCE();

        // ---- L3 ----
        a0 = *(const half8*)(H + c*HP +      8*g);
        a1 = *(const half8*)(H + c*HP + 32 + 8*g);
        float4v acc3[4];
        #pragma unroll
        for (int t = 0; t < 4; ++t) {
            const half8 w0f = *(const half8*)(Wl + ((12 + t)*64 + lane)*8);
            const half8 w1f = *(const half8*)(Wl + ((16 + t)*64 + lane)*8);
            float4v a = __builtin_amdgcn_mfma_f32_16x16x32_f16(w0f, a0, b3f[t], 0, 0, 0);
            acc3[t]   = __builtin_amdgcn_mfma_f32_16x16x32_f16(w1f, a1, a,      0, 0, 0);
        }
        #pragma unroll
        for (int t = 0; t < 4; ++t) {
            union { _Float16 h[4]; float2 f2; } u;
            #pragma unroll
            for (int r = 0; r < 4; ++r) {
                const float v = acc3[t][r];
                u.h[r] = (_Float16)(v > 0.f ? v : 0.01f * v);
            }
            *(float2*)(H + c*HP + 16*t + 4*g) = u.f2;
        }
        DS_FENCE();

        // ---- L4 ----
        a0 = *(const half8*)(H + c*HP +      8*g);
        a1 = *(const half8*)(H + c*HP + 32 + 8*g);
        const half8 w40 = *(const half8*)(Wl + (20*64 + lane)*8);
        const half8 w41 = *(const half8*)(Wl + (21*64 + lane)*8);
        float4v o = __builtin_amdgcn_mfma_f32_16x16x32_f16(w40, a0, b4f, 0, 0, 0);
        o         = __builtin_amdgcn_mfma_f32_16x16x32_f16(w41, a1, o,   0, 0, 0);
        if (g == 0) {
            const int p = base_pt + it * 16 + c;
            float* op = out + (size_t)3 * p;
            op[0] = fmaxf(o[0], 0.f);
            op[1] = fmaxf(o[1], 0.f);
            op[2] = fmaxf(o[2], 0.f);
        }
    }
}

extern "C" void kernel_launch(void* const* d_in, const int* in_sizes, int n_in,
                              void* d_out, int out_size, void* d_ws, size_t ws_size,
                              hipStream_t stream) {
    const float2* X     = (const float2*)d_in[0];
    const float2* table = (const float2*)d_in[1];
    const float*  W1    = (const float*)d_in[2];
    const float*  b1    = (const float*)d_in[3];
    const float*  W2    = (const float*)d_in[4];
    const float*  b2    = (const float*)d_in[5];
    const float*  W3    = (const float*)d_in[6];
    const float*  b3    = (const float*)d_in[7];
    const float*  W4    = (const float*)d_in[8];
    const float*  b4    = (const float*)d_in[9];
    float* out          = (float*)d_out;

    const int npts = in_sizes[0] / 2;

    // N_l = floor(float32(16 * b^l)), b computed in double (matches numpy);
    // off[l] = prefix sum of (N_l + 1) for the staged LDS tables.
    Meta mv;
    const double bg = exp((log(1024.0) - log(16.0)) / 15.0);
    int acc = 0;
    for (int l = 0; l < 16; ++l) {
        const float nl = floorf((float)(16.0 * pow(bg, (double)l)));
        mv.n[l]   = nl;
        mv.off[l] = (float)acc;
        acc += (int)nl + 1;
    }

    _Float16* wsW = (_Float16*)d_ws;
    float*    wsB = (float*)((char*)d_ws + 22528);

    prep_weights<<<45, 256, 0, stream>>>(W1, b1, W2, b2, W3, b3, W4, b4, wsW, wsB, mv);
    fused_hashnerf_mfma<<<npts / PTS_PER_BLOCK, BLK, 0, stream>>>(X, table, (const uint4*)d_ws, out);
}